// Round 1
// baseline (544.249 us; speedup 1.0000x reference)
//
#include <hip/hip_runtime.h>
#include <hip/hip_bf16.h>
#include <math.h>

#define NC 19683
#define KN 26
#define DD 128
#define HGN 64
#define LDSB 136
#define DTC 0.1f

using bf8v = __attribute__((ext_vector_type(8))) short;
using f4v  = __attribute__((ext_vector_type(4))) float;

__device__ __forceinline__ unsigned short f2bf(float x) {
    union { float f; unsigned u; } v; v.f = x;
    unsigned r = v.u + 0x7fffu + ((v.u >> 16) & 1u);
    return (unsigned short)(r >> 16);
}

// ---------------- prep: transpose 4x [256,128] f32 weights -> [128][256] bf16 ----------------
__global__ __launch_bounds__(256) void k_prep(const float* __restrict__ Wl,
    const float* __restrict__ Wm, const float* __restrict__ Wu,
    const float* __restrict__ Wc, unsigned short* __restrict__ WT)
{
    int idx = blockIdx.x * 256 + threadIdx.x;   // 4*128*256 = 131072 exact
    int m = idx >> 15;
    int r = idx & 32767;
    int j = r >> 8;     // 0..127 (output col of original W)
    int i = r & 255;    // 0..255 (k index)
    const float* src = (m == 0) ? Wl : (m == 1) ? Wm : (m == 2) ? Wu : Wc;
    WT[idx] = f2bf(src[i * DD + j]);
}

// ---------------- kA: P = cur @ Wm1 + b_msg  (MFMA), gates (fp32) ----------------
__global__ __launch_bounds__(256) void kA(const float* __restrict__ cur,
    const unsigned short* __restrict__ WT, const float* __restrict__ b_msg,
    const float* __restrict__ Wg1, const float* __restrict__ bg1,
    const float* __restrict__ Wg2, const float* __restrict__ bg2,
    float* __restrict__ P, float* __restrict__ gates)
{
    __shared__ __align__(16) unsigned short Al[32][LDSB];
    __shared__ __align__(16) unsigned short Bl[128][LDSB];
    __shared__ float curf[32][DD];
    __shared__ float hrelu[32][HGN];
    int t = threadIdx.x;
    int n0 = blockIdx.x * 32;

    for (int p = 0; p < 16; ++p) {
        int idx = p * 256 + t;
        int r = idx >> 7, c = idx & 127;
        float v = (n0 + r < NC) ? cur[(size_t)(n0 + r) * DD + c] : 0.f;
        curf[r][c] = v;
        Al[r][c] = f2bf(v);
    }
    const unsigned short* WmT = WT + 1 * 32768;   // W_msgT [128][256]; cols 0..127 = cur part
    for (int p = 0; p < 8; ++p) {
        int ch = p * 256 + t;
        int j = ch >> 4, i8 = (ch & 15) * 8;
        *(bf8v*)&Bl[j][i8] = *(const bf8v*)&WmT[j * 256 + i8];
    }
    __syncthreads();

    int w = t >> 6, lane = t & 63;
    int mt = w & 1, colh = w >> 1;
    int lm = lane & 15, lq = lane >> 4;
    for (int nt = 0; nt < 4; ++nt) {
        int col0 = colh * 64 + nt * 16;
        f4v acc = {0.f, 0.f, 0.f, 0.f};
        for (int s = 0; s < 4; ++s) {
            bf8v a = *(const bf8v*)&Al[mt * 16 + lm][s * 32 + lq * 8];
            bf8v b = *(const bf8v*)&Bl[col0 + lm][s * 32 + lq * 8];
            acc = __builtin_amdgcn_mfma_f32_16x16x32_bf16(a, b, acc, 0, 0, 0);
        }
        int col = col0 + lm;
        float bm = b_msg[col];
        for (int r = 0; r < 4; ++r) {
            int row = mt * 16 + lq * 4 + r;
            int n = n0 + row;
            if (n < NC) P[(size_t)n * DD + col] = acc[r] + bm;
        }
    }

    // gates: h = relu(cur@Wg1+bg1) fp32
    for (int p = 0; p < 8; ++p) {
        int idx = p * 256 + t;
        int c = idx >> 6, g = idx & 63;
        float s = bg1[g];
        for (int i = 0; i < DD; ++i) s += curf[c][i] * Wg1[i * HGN + g];
        hrelu[c][g] = fmaxf(s, 0.f);
    }
    __syncthreads();
    if (t < 32) {
        int n = n0 + t;
        if (n < NC) {
            float l[3];
            for (int e = 0; e < 3; ++e) {
                float s = bg2[e];
                for (int g = 0; g < HGN; ++g) s += hrelu[t][g] * Wg2[g * 3 + e];
                l[e] = s;
            }
            float m = fmaxf(l[0], fmaxf(l[1], l[2]));
            float e0 = expf(l[0] - m), e1 = expf(l[1] - m), e2 = expf(l[2] - m);
            float inv = 1.f / (e0 + e1 + e2);
            gates[n * 4 + 0] = e0 * inv;
            gates[n * 4 + 1] = e1 * inv;
            gates[n * 4 + 2] = e2 * inv;
        }
    }
}

// ---------------- kB: edge pass. 2 cells/block. agg_l, agg_d (fp32), agg_msg (MFMA+relu+mask) ----
__global__ __launch_bounds__(256) void kB(const float* __restrict__ nbr,
    const int* __restrict__ conn, const unsigned short* __restrict__ WT,
    const float* __restrict__ P, float* __restrict__ agg_l,
    float* __restrict__ agg_m, float* __restrict__ agg_d)
{
    __shared__ __align__(16) unsigned short Bl[128][LDSB];   // Wm2T[n][k]
    __shared__ __align__(16) unsigned short Al[2][32][LDSB]; // nbr rows bf16 (pad rows 26..31 = 0)
    __shared__ float pbuf[2][DD];
    __shared__ float mlm[2][32], mfm[2][32], mdm[2][32];
    __shared__ float icnt[2][4];
    int t = threadIdx.x;
    int n0 = blockIdx.x * 2;

    if (t < 64) {
        int c = t >> 5, k = t & 31;
        float vl = 0.f, vf = 0.f, vd = 0.f;
        if (k < KN && n0 + c < NC) {
            int ct = conn[(size_t)(n0 + c) * KN + k];
            vl = (ct == 0) ? 1.f : 0.f;
            vf = (ct == 1) ? 1.f : 0.f;
            vd = (ct == 2) ? 1.f : 0.f;
        }
        mlm[c][k] = vl; mfm[c][k] = vf; mdm[c][k] = vd;
    }
    {
        int c = t >> 7, j = t & 127;
        pbuf[c][j] = (n0 + c < NC) ? P[(size_t)(n0 + c) * DD + j] : 0.f;
    }
    const unsigned short* Wm2T = WT + 32768 + 128;   // W_msgT cols 128..255 = nbr part
    for (int p = 0; p < 8; ++p) {
        int ch = p * 256 + t;
        int j = ch >> 4, i8 = (ch & 15) * 8;
        *(bf8v*)&Bl[j][i8] = *(const bf8v*)&Wm2T[j * 256 + i8];
    }
    __syncthreads();   // #1: masks, pbuf, Bl visible

    if (t < 2) {
        float cl = 0.f, cf = 0.f, cd = 0.f;
        for (int k = 0; k < KN; ++k) { cl += mlm[t][k]; cf += mfm[t][k]; cd += mdm[t][k]; }
        icnt[t][0] = 1.f / fmaxf(cl, 1.f);
        icnt[t][1] = 1.f / fmaxf(cf, 1.f);
        icnt[t][2] = 1.f / fmaxf(cd, 1.f);
    }

    int c = t >> 7, j = t & 127;
    float sl = 0.f, sd = 0.f;
    if (n0 + c < NC) {
        const float* base = nbr + (size_t)(n0 + c) * KN * DD + j;
        #pragma unroll
        for (int k = 0; k < KN; ++k) {
            float v = base[(size_t)k * DD];
            sl += mlm[c][k] * v;
            sd += mdm[c][k] * v;
            Al[c][k][j] = f2bf(v);
        }
    } else {
        for (int k = 0; k < KN; ++k) Al[c][k][j] = 0;
    }
    for (int k = KN; k < 32; ++k) Al[c][k][j] = 0;
    __syncthreads();   // #2: Al, icnt visible

    if (n0 + c < NC) {
        agg_l[(size_t)(n0 + c) * DD + j] = sl * icnt[c][0];
        agg_d[(size_t)(n0 + c) * DD + j] = sd * icnt[c][2];
    }

    int w = t >> 6, lane = t & 63;
    int cc = w >> 1, colh = w & 1;
    int lm = lane & 15, lq = lane >> 4;
    if (n0 + cc < NC) {
        float icf = icnt[cc][1];
        for (int nt = 0; nt < 4; ++nt) {
            int col0 = colh * 64 + nt * 16;
            float pv = pbuf[cc][col0 + lm];
            float msum = 0.f;
            for (int mtile = 0; mtile < 2; ++mtile) {
                f4v acc = {0.f, 0.f, 0.f, 0.f};
                for (int s = 0; s < 4; ++s) {
                    bf8v a = *(const bf8v*)&Al[cc][mtile * 16 + lm][s * 32 + lq * 8];
                    bf8v b = *(const bf8v*)&Bl[col0 + lm][s * 32 + lq * 8];
                    acc = __builtin_amdgcn_mfma_f32_16x16x32_bf16(a, b, acc, 0, 0, 0);
                }
                for (int r = 0; r < 4; ++r) {
                    int row = mtile * 16 + lq * 4 + r;
                    if (mfm[cc][row] > 0.f) msum += fmaxf(pv + acc[r], 0.f);
                }
            }
            msum += __shfl_xor(msum, 16, 64);
            msum += __shfl_xor(msum, 32, 64);
            if (lane < 16) agg_m[(size_t)(n0 + cc) * DD + col0 + lane] = msum * icf;
        }
    }
}

// ---------------- kC: experts + gated combine. 32 cells/block ----------------
__global__ __launch_bounds__(256) void kC(const float* __restrict__ cur,
    const unsigned short* __restrict__ WT, const float* __restrict__ agg_l,
    const float* __restrict__ agg_m, const float* __restrict__ agg_d,
    const float* __restrict__ b_local, const float* __restrict__ b_upd,
    const float* __restrict__ b_cnf, const float* __restrict__ gates,
    float* __restrict__ out)
{
    __shared__ __align__(16) unsigned short Wl[128][LDSB];
    __shared__ __align__(16) unsigned short Xc[32][LDSB];
    __shared__ __align__(16) unsigned short Xa[32][LDSB];
    __shared__ float glds[32][4];
    __shared__ float bl[DD], bu[DD], bc[DD];
    int t = threadIdx.x;
    int n0 = blockIdx.x * 32;
    int w = t >> 6, lane = t & 63;
    int mt = w & 1, colh = w >> 1;
    int lm = lane & 15, lq = lane >> 4;

    auto stageW = [&](int m, int koff) {
        const unsigned short* src = WT + m * 32768 + koff;
        for (int p = 0; p < 8; ++p) {
            int ch = p * 256 + t;
            int j = ch >> 4, i8 = (ch & 15) * 8;
            *(bf8v*)&Wl[j][i8] = *(const bf8v*)&src[j * 256 + i8];
        }
    };
    auto stageXa = [&](const float* src) {
        for (int p = 0; p < 16; ++p) {
            int idx = p * 256 + t;
            int r = idx >> 7, ccol = idx & 127;
            float v = (n0 + r < NC) ? src[(size_t)(n0 + r) * DD + ccol] : 0.f;
            Xa[r][ccol] = f2bf(v);
        }
    };
    auto mfmaPass = [&](unsigned short (&X)[32][LDSB], f4v* acc) {
        for (int nt = 0; nt < 4; ++nt) {
            int col0 = colh * 64 + nt * 16;
            for (int s = 0; s < 4; ++s) {
                bf8v a = *(const bf8v*)&X[mt * 16 + lm][s * 32 + lq * 8];
                bf8v b = *(const bf8v*)&Wl[col0 + lm][s * 32 + lq * 8];
                acc[nt] = __builtin_amdgcn_mfma_f32_16x16x32_bf16(a, b, acc[nt], 0, 0, 0);
            }
        }
    };

    // stage Xc, biases, gates, W_local chunk1
    for (int p = 0; p < 16; ++p) {
        int idx = p * 256 + t;
        int r = idx >> 7, ccol = idx & 127;
        float v = (n0 + r < NC) ? cur[(size_t)(n0 + r) * DD + ccol] : 0.f;
        Xc[r][ccol] = f2bf(v);
    }
    if (t < 128) { bl[t] = b_local[t]; bu[t] = b_upd[t]; bc[t] = b_cnf[t]; }
    if (t >= 128 && t < 160) {
        int r = t - 128; int n = n0 + r;
        float g0 = 0.f, g1 = 0.f, g2 = 0.f;
        if (n < NC) { g0 = gates[n * 4]; g1 = gates[n * 4 + 1]; g2 = gates[n * 4 + 2]; }
        glds[r][0] = g0; glds[r][1] = g1; glds[r][2] = g2;
    }
    stageW(0, 0);
    __syncthreads();

    f4v oacc[4], acc[4];
    for (int nt = 0; nt < 4; ++nt) oacc[nt] = (f4v){0.f, 0.f, 0.f, 0.f};

    // --- local expert ---
    for (int nt = 0; nt < 4; ++nt) acc[nt] = (f4v){0.f, 0.f, 0.f, 0.f};
    mfmaPass(Xc, acc);
    __syncthreads();
    stageW(0, 128); stageXa(agg_l);
    __syncthreads();
    mfmaPass(Xa, acc);
    for (int nt = 0; nt < 4; ++nt) {
        int col = colh * 64 + nt * 16 + lm;
        for (int r = 0; r < 4; ++r) {
            int row = mt * 16 + lq * 4 + r;
            oacc[nt][r] += glds[row][0] * tanhf(acc[nt][r] + bl[col]);
        }
    }

    // --- functional expert ---
    __syncthreads();
    stageW(2, 0);
    __syncthreads();
    for (int nt = 0; nt < 4; ++nt) acc[nt] = (f4v){0.f, 0.f, 0.f, 0.f};
    mfmaPass(Xc, acc);
    __syncthreads();
    stageW(2, 128); stageXa(agg_m);
    __syncthreads();
    mfmaPass(Xa, acc);
    for (int nt = 0; nt < 4; ++nt) {
        int col = colh * 64 + nt * 16 + lm;
        for (int r = 0; r < 4; ++r) {
            int row = mt * 16 + lq * 4 + r;
            oacc[nt][r] += glds[row][1] * tanhf(acc[nt][r] + bu[col]);
        }
    }

    // --- distant expert (CNF) ---
    __syncthreads();
    stageW(3, 128); stageXa(agg_d);
    __syncthreads();
    for (int nt = 0; nt < 4; ++nt) acc[nt] = (f4v){0.f, 0.f, 0.f, 0.f};
    mfmaPass(Xa, acc);
    f4v hd[4], s[4];
    for (int nt = 0; nt < 4; ++nt) {
        int col = colh * 64 + nt * 16 + lm;
        for (int r = 0; r < 4; ++r) {
            int row = mt * 16 + lq * 4 + r;
            int n = n0 + row;
            hd[nt][r] = acc[nt][r] + bc[col];
            s[nt][r] = (n < NC) ? cur[(size_t)n * DD + col] : 0.f;
        }
    }
    __syncthreads();
    stageW(3, 0);   // Wc1, persists across steps
    for (int step = 0; step < 3; ++step) {
        for (int nt = 0; nt < 4; ++nt) {
            int col = colh * 64 + nt * 16 + lm;
            for (int r = 0; r < 4; ++r) {
                int row = mt * 16 + lq * 4 + r;
                Xa[row][col] = f2bf(s[nt][r]);
            }
        }
        __syncthreads();
        for (int nt = 0; nt < 4; ++nt) acc[nt] = (f4v){0.f, 0.f, 0.f, 0.f};
        mfmaPass(Xa, acc);
        for (int nt = 0; nt < 4; ++nt)
            for (int r = 0; r < 4; ++r)
                s[nt][r] += DTC * tanhf(acc[nt][r] + hd[nt][r]);
        __syncthreads();
    }

    // --- combine + store ---
    for (int nt = 0; nt < 4; ++nt) {
        int col = colh * 64 + nt * 16 + lm;
        for (int r = 0; r < 4; ++r) {
            int row = mt * 16 + lq * 4 + r;
            int n = n0 + row;
            if (n < NC) out[(size_t)n * DD + col] = oacc[nt][r] + glds[row][2] * s[nt][r];
        }
    }
}

extern "C" void kernel_launch(void* const* d_in, const int* in_sizes, int n_in,
                              void* d_out, int out_size, void* d_ws, size_t ws_size,
                              hipStream_t stream) {
    const float* cur     = (const float*)d_in[0];
    const float* nbr     = (const float*)d_in[1];
    const int*   conn    = (const int*)d_in[2];
    const float* W_local = (const float*)d_in[3];
    const float* b_local = (const float*)d_in[4];
    const float* W_msg   = (const float*)d_in[5];
    const float* b_msg   = (const float*)d_in[6];
    const float* W_upd   = (const float*)d_in[7];
    const float* b_upd   = (const float*)d_in[8];
    const float* W_cnf   = (const float*)d_in[9];
    const float* b_cnf   = (const float*)d_in[10];
    const float* Wg1     = (const float*)d_in[11];
    const float* bg1     = (const float*)d_in[12];
    const float* Wg2     = (const float*)d_in[13];
    const float* bg2     = (const float*)d_in[14];
    float* out = (float*)d_out;

    char* ws = (char*)d_ws;
    unsigned short* WT = (unsigned short*)ws;                       // 262144 B
    float* P     = (float*)(ws + 262144);                           // 10077696 B
    float* gatesb = (float*)(ws + 262144 + 10077696);               // 314928 B
    float* aggl  = (float*)(ws + 262144 + 10077696 + 314928);
    float* aggm  = aggl + (size_t)NC * DD;
    float* aggd  = aggm + (size_t)NC * DD;

    hipLaunchKernelGGL(k_prep, dim3(512), dim3(256), 0, stream, W_local, W_msg, W_upd, W_cnf, WT);
    hipLaunchKernelGGL(kA, dim3(616), dim3(256), 0, stream, cur, WT, b_msg, Wg1, bg1, Wg2, bg2, P, gatesb);
    hipLaunchKernelGGL(kB, dim3(9842), dim3(256), 0, stream, nbr, conn, WT, P, aggl, aggm, aggd);
    hipLaunchKernelGGL(kC, dim3(616), dim3(256), 0, stream, cur, WT, aggl, aggm, aggd, b_local, b_upd, b_cnf, gatesb, out);
}

// Round 2
// 457.788 us; speedup vs baseline: 1.1889x; 1.1889x over previous
//
#include <hip/hip_runtime.h>
#include <hip/hip_bf16.h>
#include <math.h>

#define NC 19683
#define KN 26
#define DD 128
#define HGN 64
#define LDSB 136
#define DTC 0.1f

using bf8v = __attribute__((ext_vector_type(8))) short;
using f4v  = __attribute__((ext_vector_type(4))) float;

__device__ __forceinline__ unsigned short f2bf(float x) {
    union { float f; unsigned u; } v; v.f = x;
    unsigned r = v.u + 0x7fffu + ((v.u >> 16) & 1u);
    return (unsigned short)(r >> 16);
}
__device__ __forceinline__ unsigned pk2(float a, float b) {
    return ((unsigned)f2bf(a)) | (((unsigned)f2bf(b)) << 16);
}

// ---------------- prep: transpose 4x [256,128] f32 weights -> [128][256] bf16; Wg1 -> [64][128] bf16 ----
__global__ __launch_bounds__(256) void k_prep(const float* __restrict__ Wl,
    const float* __restrict__ Wm, const float* __restrict__ Wu,
    const float* __restrict__ Wc, const float* __restrict__ Wg1,
    unsigned short* __restrict__ WT, unsigned short* __restrict__ WgT)
{
    int idx = blockIdx.x * 256 + threadIdx.x;   // 544*256 = 139264 exact
    if (idx < 131072) {
        int m = idx >> 15;
        int r = idx & 32767;
        int j = r >> 8;     // 0..127 output col
        int i = r & 255;    // 0..255 k
        const float* src = (m == 0) ? Wl : (m == 1) ? Wm : (m == 2) ? Wu : Wc;
        WT[idx] = f2bf(src[i * DD + j]);
    } else {
        int idx2 = idx - 131072;        // 0..8191
        int col = idx2 >> 7;            // 0..63
        int k = idx2 & 127;             // 0..127
        WgT[idx2] = f2bf(Wg1[k * HGN + col]);
    }
}

// ---------------- kA: P = cur @ Wm1 + b_msg (MFMA), gates (MFMA h + fp32 head) ----------------
__global__ __launch_bounds__(256) void kA(const float* __restrict__ cur,
    const unsigned short* __restrict__ WT, const unsigned short* __restrict__ WgT,
    const float* __restrict__ b_msg, const float* __restrict__ bg1,
    const float* __restrict__ Wg2, const float* __restrict__ bg2,
    float* __restrict__ P, float* __restrict__ gates)
{
    __shared__ __align__(16) unsigned short Al[32][LDSB];
    __shared__ __align__(16) unsigned short Bl[128][LDSB];
    __shared__ __align__(16) unsigned short Gl[64][LDSB];
    __shared__ float hrelu[32][HGN + 4];
    int t = threadIdx.x;
    int n0 = blockIdx.x * 32;
    int w = t >> 6, lane = t & 63;
    int lm = lane & 15, lq = lane >> 4;

    // stage cur -> Al bf16 (float2 loads)
    for (int p = 0; p < 8; ++p) {
        int idx = p * 256 + t;
        int r = idx >> 6, c2 = (idx & 63) * 2;
        float2 v = {0.f, 0.f};
        if (n0 + r < NC) v = *(const float2*)&cur[(size_t)(n0 + r) * DD + c2];
        *(unsigned*)&Al[r][c2] = pk2(v.x, v.y);
    }
    // stage W_msg first half (cur part): Bl[col][k0..127]
    const unsigned short* WmT = WT + 32768;
    for (int p = 0; p < 8; ++p) {
        int ch = p * 256 + t;
        int j = ch >> 4, i8 = (ch & 15) * 8;
        *(bf8v*)&Bl[j][i8] = *(const bf8v*)&WmT[j * 256 + i8];
    }
    // stage WgT [64][128]
    for (int p = 0; p < 4; ++p) {
        int ch = p * 256 + t;
        int j = ch >> 4, i8 = (ch & 15) * 8;
        *(bf8v*)&Gl[j][i8] = *(const bf8v*)&WgT[j * 128 + i8];
    }
    __syncthreads();

    // P MFMA: waves (mt, colh)
    {
        int mt = w & 1, colh = w >> 1;
        for (int nt = 0; nt < 4; ++nt) {
            int col0 = colh * 64 + nt * 16;
            f4v acc = {0.f, 0.f, 0.f, 0.f};
            for (int s = 0; s < 4; ++s) {
                bf8v a = *(const bf8v*)&Al[mt * 16 + lm][s * 32 + lq * 8];
                bf8v b = *(const bf8v*)&Bl[col0 + lm][s * 32 + lq * 8];
                acc = __builtin_amdgcn_mfma_f32_16x16x32_bf16(a, b, acc, 0, 0, 0);
            }
            int col = col0 + lm;
            float bm = b_msg[col];
            for (int r = 0; r < 4; ++r) {
                int row = mt * 16 + lq * 4 + r;
                int n = n0 + row;
                if (n < NC) P[(size_t)n * DD + col] = acc[r] + bm;
            }
        }
    }
    // gating h MFMA: wave w -> col-tile w (cols w*16..w*16+15 of 64)
    {
        int col0 = w * 16;
        float bg = bg1[col0 + lm];
        for (int mt2 = 0; mt2 < 2; ++mt2) {
            f4v acc = {0.f, 0.f, 0.f, 0.f};
            for (int s = 0; s < 4; ++s) {
                bf8v a = *(const bf8v*)&Al[mt2 * 16 + lm][s * 32 + lq * 8];
                bf8v b = *(const bf8v*)&Gl[col0 + lm][s * 32 + lq * 8];
                acc = __builtin_amdgcn_mfma_f32_16x16x32_bf16(a, b, acc, 0, 0, 0);
            }
            for (int r = 0; r < 4; ++r)
                hrelu[mt2 * 16 + lq * 4 + r][col0 + lm] = fmaxf(acc[r] + bg, 0.f);
        }
    }
    __syncthreads();
    if (t < 32) {
        int n = n0 + t;
        if (n < NC) {
            float l[3];
            for (int e = 0; e < 3; ++e) {
                float s = bg2[e];
                for (int g = 0; g < HGN; ++g) s += hrelu[t][g] * Wg2[g * 3 + e];
                l[e] = s;
            }
            float m = fmaxf(l[0], fmaxf(l[1], l[2]));
            float e0 = expf(l[0] - m), e1 = expf(l[1] - m), e2 = expf(l[2] - m);
            float inv = 1.f / (e0 + e1 + e2);
            gates[n * 4 + 0] = e0 * inv;
            gates[n * 4 + 1] = e1 * inv;
            gates[n * 4 + 2] = e2 * inv;
        }
    }
}

// ---------------- kB: edge pass. 4 cells/block, wave w = cell w, ballot masks, bf16 agg out ----
__global__ __launch_bounds__(256) void kB(const float* __restrict__ nbr,
    const int* __restrict__ conn, const unsigned short* __restrict__ WT,
    const float* __restrict__ P, unsigned short* __restrict__ agg_l,
    unsigned short* __restrict__ agg_m, unsigned short* __restrict__ agg_d)
{
    __shared__ __align__(16) unsigned short Bl[128][LDSB];   // Wm2T[col][k]
    __shared__ __align__(16) unsigned short Al[4][32][LDSB]; // nbr bf16, rows 26..31 zero
    __shared__ float P8[4][DD];
    int t = threadIdx.x;
    int n0 = blockIdx.x * 4;
    int w = t >> 6, lane = t & 63;
    int n = n0 + w;                 // wave w handles cell w
    bool act = n < NC;

    // W staging (L2)
    const unsigned short* Wm2T = WT + 32768 + 128;
    for (int p = 0; p < 8; ++p) {
        int ch = p * 256 + t;
        int j = ch >> 4, i8 = (ch & 15) * 8;
        *(bf8v*)&Bl[j][i8] = *(const bf8v*)&Wm2T[j * 256 + i8];
    }
    // P staging (float2)
    {
        int idx = t * 2;
        int r = idx >> 7, c = idx & 127;
        float2 v = {0.f, 0.f};
        if (n0 + r < NC) v = *(const float2*)&P[(size_t)(n0 + r) * DD + c];
        *(float2*)&P8[r][c] = v;
    }
    // conn -> wave-uniform ballot masks
    int ct = 3;
    if (act && lane < KN) ct = conn[(size_t)n * KN + lane];
    unsigned long long mlb = __ballot(ct == 0);
    unsigned long long mfb = __ballot(ct == 1);
    unsigned long long mdb = __ballot(ct == 2);
    float icl = 1.f / fmaxf((float)__builtin_popcountll(mlb), 1.f);
    float icf = 1.f / fmaxf((float)__builtin_popcountll(mfb), 1.f);
    float icd = 1.f / fmaxf((float)__builtin_popcountll(mdb), 1.f);

    // nbr loads: thread owns cols (2*lane, 2*lane+1) of its cell
    int j2 = lane * 2;
    const float* base = nbr + ((size_t)(act ? n : 0) * KN) * DD + j2;
    float2 vv[KN];
    #pragma unroll
    for (int k = 0; k < KN; ++k) {
        float2 v = {0.f, 0.f};
        if (act) v = *(const float2*)&base[(size_t)k * DD];
        vv[k] = v;
    }
    float slx = 0.f, sly = 0.f, sdx = 0.f, sdy = 0.f;
    #pragma unroll
    for (int k = 0; k < KN; ++k) {
        float2 v = vv[k];
        if ((mlb >> k) & 1) { slx += v.x; sly += v.y; }
        if ((mdb >> k) & 1) { sdx += v.x; sdy += v.y; }
        *(unsigned*)&Al[w][k][j2] = pk2(v.x, v.y);
    }
    // zero pad rows 26..31 (contiguous 6*LDSB shorts per cell)
    {
        unsigned* pz = (unsigned*)&Al[w][KN][0];
        for (int z = lane; z < (32 - KN) * LDSB / 2; z += 64) pz[z] = 0;
    }
    if (act) {
        *(unsigned*)&agg_l[(size_t)n * DD + j2] = pk2(slx * icl, sly * icl);
        *(unsigned*)&agg_d[(size_t)n * DD + j2] = pk2(sdx * icd, sdy * icd);
    }
    __syncthreads();

    // msg MFMA: wave w does all 8 col-tiles of its cell
    if (act) {
        int lm = lane & 15, lq = lane >> 4;
        for (int nt = 0; nt < 8; ++nt) {
            int col0 = nt * 16;
            float pv = P8[w][col0 + lm];
            float msum = 0.f;
            for (int mt2 = 0; mt2 < 2; ++mt2) {
                f4v acc = {0.f, 0.f, 0.f, 0.f};
                for (int s = 0; s < 4; ++s) {
                    bf8v a = *(const bf8v*)&Al[w][mt2 * 16 + lm][s * 32 + lq * 8];
                    bf8v b = *(const bf8v*)&Bl[col0 + lm][s * 32 + lq * 8];
                    acc = __builtin_amdgcn_mfma_f32_16x16x32_bf16(a, b, acc, 0, 0, 0);
                }
                for (int r = 0; r < 4; ++r) {
                    int row = mt2 * 16 + lq * 4 + r;
                    if ((mfb >> row) & 1) msum += fmaxf(pv + acc[r], 0.f);
                }
            }
            msum += __shfl_xor(msum, 16, 64);
            msum += __shfl_xor(msum, 32, 64);
            if (lane < 16) agg_m[(size_t)n * DD + col0 + lane] = f2bf(msum * icf);
        }
    }
}

// ---------------- kC: experts + gated combine. 32 cells/block, bf16 agg in ----------------
__global__ __launch_bounds__(256) void kC(const float* __restrict__ cur,
    const unsigned short* __restrict__ WT, const unsigned short* __restrict__ agg_l,
    const unsigned short* __restrict__ agg_m, const unsigned short* __restrict__ agg_d,
    const float* __restrict__ b_local, const float* __restrict__ b_upd,
    const float* __restrict__ b_cnf, const float* __restrict__ gates,
    float* __restrict__ out)
{
    __shared__ __align__(16) unsigned short Wl[128][LDSB];
    __shared__ __align__(16) unsigned short Xc[32][LDSB];
    __shared__ __align__(16) unsigned short Xa[32][LDSB];
    __shared__ float glds[32][4];
    __shared__ float bl[DD], bu[DD], bc[DD];
    int t = threadIdx.x;
    int n0 = blockIdx.x * 32;
    int w = t >> 6, lane = t & 63;
    int mt = w & 1, colh = w >> 1;
    int lm = lane & 15, lq = lane >> 4;

    auto stageW = [&](int m, int koff) {
        const unsigned short* src = WT + m * 32768 + koff;
        for (int p = 0; p < 8; ++p) {
            int ch = p * 256 + t;
            int j = ch >> 4, i8 = (ch & 15) * 8;
            *(bf8v*)&Wl[j][i8] = *(const bf8v*)&src[j * 256 + i8];
        }
    };
    auto stageXa = [&](const unsigned short* src) {
        for (int p = 0; p < 2; ++p) {
            int idx = p * 256 + t;
            int r = idx >> 4, c8 = (idx & 15) * 8;
            bf8v v = {0, 0, 0, 0, 0, 0, 0, 0};
            if (n0 + r < NC) v = *(const bf8v*)&src[(size_t)(n0 + r) * DD + c8];
            *(bf8v*)&Xa[r][c8] = v;
        }
    };
    auto mfmaPass = [&](unsigned short (&X)[32][LDSB], f4v* acc) {
        for (int nt = 0; nt < 4; ++nt) {
            int col0 = colh * 64 + nt * 16;
            for (int s = 0; s < 4; ++s) {
                bf8v a = *(const bf8v*)&X[mt * 16 + lm][s * 32 + lq * 8];
                bf8v b = *(const bf8v*)&Wl[col0 + lm][s * 32 + lq * 8];
                acc[nt] = __builtin_amdgcn_mfma_f32_16x16x32_bf16(a, b, acc[nt], 0, 0, 0);
            }
        }
    };

    // stage Xc (cur bf16, float2 loads), biases, gates, W_local chunk1
    for (int p = 0; p < 8; ++p) {
        int idx = p * 256 + t;
        int r = idx >> 6, c2 = (idx & 63) * 2;
        float2 v = {0.f, 0.f};
        if (n0 + r < NC) v = *(const float2*)&cur[(size_t)(n0 + r) * DD + c2];
        *(unsigned*)&Xc[r][c2] = pk2(v.x, v.y);
    }
    if (t < 128) { bl[t] = b_local[t]; bu[t] = b_upd[t]; bc[t] = b_cnf[t]; }
    if (t >= 128 && t < 160) {
        int r = t - 128; int n = n0 + r;
        float g0 = 0.f, g1 = 0.f, g2 = 0.f;
        if (n < NC) { g0 = gates[n * 4]; g1 = gates[n * 4 + 1]; g2 = gates[n * 4 + 2]; }
        glds[r][0] = g0; glds[r][1] = g1; glds[r][2] = g2;
    }
    stageW(0, 0);
    __syncthreads();

    f4v oacc[4], acc[4];
    for (int nt = 0; nt < 4; ++nt) oacc[nt] = (f4v){0.f, 0.f, 0.f, 0.f};

    // --- local expert ---
    for (int nt = 0; nt < 4; ++nt) acc[nt] = (f4v){0.f, 0.f, 0.f, 0.f};
    mfmaPass(Xc, acc);
    __syncthreads();
    stageW(0, 128); stageXa(agg_l);
    __syncthreads();
    mfmaPass(Xa, acc);
    for (int nt = 0; nt < 4; ++nt) {
        int col = colh * 64 + nt * 16 + lm;
        for (int r = 0; r < 4; ++r) {
            int row = mt * 16 + lq * 4 + r;
            oacc[nt][r] += glds[row][0] * tanhf(acc[nt][r] + bl[col]);
        }
    }

    // --- functional expert ---
    __syncthreads();
    stageW(2, 0);
    __syncthreads();
    for (int nt = 0; nt < 4; ++nt) acc[nt] = (f4v){0.f, 0.f, 0.f, 0.f};
    mfmaPass(Xc, acc);
    __syncthreads();
    stageW(2, 128); stageXa(agg_m);
    __syncthreads();
    mfmaPass(Xa, acc);
    for (int nt = 0; nt < 4; ++nt) {
        int col = colh * 64 + nt * 16 + lm;
        for (int r = 0; r < 4; ++r) {
            int row = mt * 16 + lq * 4 + r;
            oacc[nt][r] += glds[row][1] * tanhf(acc[nt][r] + bu[col]);
        }
    }

    // --- distant expert (CNF) ---
    __syncthreads();
    stageW(3, 128); stageXa(agg_d);
    __syncthreads();
    for (int nt = 0; nt < 4; ++nt) acc[nt] = (f4v){0.f, 0.f, 0.f, 0.f};
    mfmaPass(Xa, acc);
    f4v hd[4], s[4];
    for (int nt = 0; nt < 4; ++nt) {
        int col = colh * 64 + nt * 16 + lm;
        for (int r = 0; r < 4; ++r) {
            int row = mt * 16 + lq * 4 + r;
            int n = n0 + row;
            hd[nt][r] = acc[nt][r] + bc[col];
            s[nt][r] = (n < NC) ? cur[(size_t)n * DD + col] : 0.f;
        }
    }
    __syncthreads();
    stageW(3, 0);   // Wc1, persists across steps
    for (int step = 0; step < 3; ++step) {
        for (int nt = 0; nt < 4; ++nt) {
            int col = colh * 64 + nt * 16 + lm;
            for (int r = 0; r < 4; ++r) {
                int row = mt * 16 + lq * 4 + r;
                Xa[row][col] = f2bf(s[nt][r]);
            }
        }
        __syncthreads();
        for (int nt = 0; nt < 4; ++nt) acc[nt] = (f4v){0.f, 0.f, 0.f, 0.f};
        mfmaPass(Xa, acc);
        for (int nt = 0; nt < 4; ++nt)
            for (int r = 0; r < 4; ++r)
                s[nt][r] += DTC * tanhf(acc[nt][r] + hd[nt][r]);
        __syncthreads();
    }

    // --- combine + store ---
    for (int nt = 0; nt < 4; ++nt) {
        int col = colh * 64 + nt * 16 + lm;
        for (int r = 0; r < 4; ++r) {
            int row = mt * 16 + lq * 4 + r;
            int n = n0 + row;
            if (n < NC) out[(size_t)n * DD + col] = oacc[nt][r] + glds[row][2] * s[nt][r];
        }
    }
}

extern "C" void kernel_launch(void* const* d_in, const int* in_sizes, int n_in,
                              void* d_out, int out_size, void* d_ws, size_t ws_size,
                              hipStream_t stream) {
    const float* cur     = (const float*)d_in[0];
    const float* nbr     = (const float*)d_in[1];
    const int*   conn    = (const int*)d_in[2];
    const float* W_local = (const float*)d_in[3];
    const float* b_local = (const float*)d_in[4];
    const float* W_msg   = (const float*)d_in[5];
    const float* b_msg   = (const float*)d_in[6];
    const float* W_upd   = (const float*)d_in[7];
    const float* b_upd   = (const float*)d_in[8];
    const float* W_cnf   = (const float*)d_in[9];
    const float* b_cnf   = (const float*)d_in[10];
    const float* Wg1     = (const float*)d_in[11];
    const float* bg1     = (const float*)d_in[12];
    const float* Wg2     = (const float*)d_in[13];
    const float* bg2     = (const float*)d_in[14];
    float* out = (float*)d_out;

    char* ws = (char*)d_ws;
    unsigned short* WT  = (unsigned short*)ws;                       // 262144 B
    unsigned short* WgT = (unsigned short*)(ws + 262144);            // 16384 B
    float* P      = (float*)(ws + 278528);                           // 10077696 B
    float* gatesb = (float*)(ws + 278528 + 10077696);                // 314928 B
    unsigned short* aggl = (unsigned short*)(ws + 278528 + 10077696 + 314928);
    unsigned short* aggm = aggl + (size_t)NC * DD;                   // 5038848 B each
    unsigned short* aggd = aggm + (size_t)NC * DD;

    hipLaunchKernelGGL(k_prep, dim3(544), dim3(256), 0, stream, W_local, W_msg, W_upd, W_cnf, Wg1, WT, WgT);
    hipLaunchKernelGGL(kA, dim3(616), dim3(256), 0, stream, cur, WT, WgT, b_msg, bg1, Wg2, bg2, P, gatesb);
    hipLaunchKernelGGL(kB, dim3(4921), dim3(256), 0, stream, nbr, conn, WT, P, aggl, aggm, aggd);
    hipLaunchKernelGGL(kC, dim3(616), dim3(256), 0, stream, cur, WT, aggl, aggm, aggd, b_local, b_upd, b_cnf, gatesb, out);
}